// Round 2
// baseline (147.913 us; speedup 1.0000x reference)
//
#include <hip/hip_runtime.h>
#include <hip/hip_bf16.h>
#include <cstdint>

#define N_PTS 8192
#define DIM 128
#define NTILE 64       // 8192 / 128
#define NBLOCKS 2080   // NTILE*(NTILE+1)/2 upper-triangle tile blocks

typedef __attribute__((ext_vector_type(8))) __bf16 bf16x8;
typedef __attribute__((ext_vector_type(4))) float f32x4;

// RNE float -> bf16 bits (inputs finite)
__device__ __forceinline__ unsigned short f2bf(float x) {
  unsigned int u = __float_as_uint(x);
  return (unsigned short)((u + 0x7FFFu + ((u >> 16) & 1u)) >> 16);
}

// lp(s) = (1.25-s)(0.75-s)*256 = 256 s^2 - 512 s + 240  (monotone decreasing for s<1)
__device__ __forceinline__ float lp_of(float s) {
  return __builtin_fmaf(s, __builtin_fmaf(s, 256.0f, -512.0f), 240.0f);
}
// ln(s) = max(s+0.25,0)*(s-0.25)*256 = 256*max(s,-0.25)^2 - 16 (exact incl. clamp)
__device__ __forceinline__ float ln_of(float s) {
  const float u = fmaxf(s, -0.25f);
  return __builtin_fmaf(u, u * 256.0f, -16.0f);
}

// One wave per row: L2-normalize (eps=1e-12), store bf16 bits.
__global__ __launch_bounds__(256) void normalize_kernel(const float* __restrict__ feat,
                                                        unsigned short* __restrict__ fb) {
  const int row = blockIdx.x * 4 + (threadIdx.x >> 6);
  const int lane = threadIdx.x & 63;
  const float2 v = *(const float2*)(feat + row * DIM + lane * 2);
  float ss = v.x * v.x + v.y * v.y;
#pragma unroll
  for (int o = 32; o > 0; o >>= 1) ss += __shfl_xor(ss, o);
  const float inv = 1.0f / fmaxf(sqrtf(ss), 1e-12f);
  const unsigned int pack =
      (unsigned int)f2bf(v.x * inv) | ((unsigned int)f2bf(v.y * inv) << 16);
  *(unsigned int*)(fb + row * DIM + lane * 2) = pack;
}

// Epilogue passes, templated on whether this is a diagonal tile (needs j>i test).
template <bool DIAG>
__device__ __forceinline__ void do_passes(const f32x4 (&acc)[4][4], const int (&li)[4][4],
                                          const int (&lj)[4], int dj, int lane, int wave,
                                          float* redbuf, float4* __restrict__ partials,
                                          int slot, int t) {
  // ---- pass 1: stream-wise s-extremes (no logit math) ----
  float mnP[4] = {1e30f, 1e30f, 1e30f, 1e30f};
  float mnN[4] = {1e30f, 1e30f, 1e30f, 1e30f};
  float mxN[4] = {-1e30f, -1e30f, -1e30f, -1e30f};
#pragma unroll
  for (int tm = 0; tm < 4; ++tm)
#pragma unroll
    for (int tn = 0; tn < 4; ++tn)
#pragma unroll
      for (int r = 0; r < 4; ++r) {
        const float s = acc[tm][tn][r];
        const bool eq = (li[tm][r] == lj[tn]);
        bool pm = eq, nm = !eq;
        if (DIAG) {
          const bool valid = (dj + tn * 16 - tm * 16 - r) > 0;
          pm = pm && valid;
          nm = nm && valid;
        }
        mnP[r] = fminf(mnP[r], pm ? s : 1e30f);
        mnN[r] = fminf(mnN[r], nm ? s : 1e30f);
        mxN[r] = fmaxf(mxN[r], nm ? s : -1e30f);
      }
  float a = fminf(fminf(mnP[0], mnP[1]), fminf(mnP[2], mnP[3]));
  float b = fminf(fminf(mnN[0], mnN[1]), fminf(mnN[2], mnN[3]));
  float c = fmaxf(fmaxf(mxN[0], mxN[1]), fmaxf(mxN[2], mxN[3]));
#pragma unroll
  for (int o = 32; o > 0; o >>= 1) {
    a = fminf(a, __shfl_xor(a, o));
    b = fminf(b, __shfl_xor(b, o));
    c = fmaxf(c, __shfl_xor(c, o));
  }
  if (lane == 0) { redbuf[wave] = a; redbuf[4 + wave] = b; redbuf[8 + wave] = c; }
  __syncthreads();
  const float mnPall = fminf(fminf(redbuf[0], redbuf[1]), fminf(redbuf[2], redbuf[3]));
  const float mnNall = fminf(fminf(redbuf[4], redbuf[5]), fminf(redbuf[6], redbuf[7]));
  const float mxNall = fmaxf(fmaxf(redbuf[8], redbuf[9]), fmaxf(redbuf[10], redbuf[11]));
  // lp monotone-decreasing -> max at min s; ln quasi-convex -> max at an endpoint.
  const float Mp = (mnPall > 1e29f) ? -1e30f : lp_of(mnPall);
  const float Mn = (mxNall < -1e29f) ? -1e30f : fmaxf(ln_of(mnNall), ln_of(mxNall));
  __syncthreads();  // redbuf reuse

  // ---- pass 2: one exp per element, masked accumulate into both streams ----
  float spA[4] = {0.f, 0.f, 0.f, 0.f}, snA[4] = {0.f, 0.f, 0.f, 0.f};
#pragma unroll
  for (int tm = 0; tm < 4; ++tm)
#pragma unroll
    for (int tn = 0; tn < 4; ++tn)
#pragma unroll
      for (int r = 0; r < 4; ++r) {
        const float s = acc[tm][tn][r];
        const bool eq = (li[tm][r] == lj[tn]);
        const float l = eq ? lp_of(s) : ln_of(s);
        const float m = eq ? Mp : Mn;
        const float e = __expf(l - m);  // masked-out lanes may produce inf; selects drop it
        bool pm = eq, nm = !eq;
        if (DIAG) {
          const bool valid = (dj + tn * 16 - tm * 16 - r) > 0;
          pm = pm && valid;
          nm = nm && valid;
        }
        spA[r] += pm ? e : 0.f;
        snA[r] += nm ? e : 0.f;
      }
  float sp = (spA[0] + spA[1]) + (spA[2] + spA[3]);
  float sn = (snA[0] + snA[1]) + (snA[2] + snA[3]);
#pragma unroll
  for (int o = 32; o > 0; o >>= 1) {
    sp += __shfl_xor(sp, o);
    sn += __shfl_xor(sn, o);
  }
  if (lane == 0) { redbuf[wave] = sp; redbuf[4 + wave] = sn; }
  __syncthreads();
  if (t == 0) {
    partials[slot] = make_float4(Mp, redbuf[0] + redbuf[1] + redbuf[2] + redbuf[3],
                                 Mn, redbuf[4] + redbuf[5] + redbuf[6] + redbuf[7]);
  }
}

// 128x128 tile per block, upper-triangle tiles only. Chunk-linear LDS layout:
// chunk index c = (row>>4)*64 + (k8)*16 + (row&15), 16 B per chunk. Fragment reads
// and global_load_lds destinations are both base + lane*16 -> conflict-free.
__global__ __launch_bounds__(256, 3) void pair_kernel(const unsigned short* __restrict__ f,
                                                      const int* __restrict__ labels,
                                                      float4* __restrict__ partials) {
  // decode linear block id -> (tI, tJ), tJ >= tI. f(i) = 64i - i(i-1)/2
  const int k = blockIdx.x;
  int tI = (int)((129.0 - sqrt(16641.0 - 8.0 * (double)k)) * 0.5);
  tI = tI < 0 ? 0 : (tI > 63 ? 63 : tI);
  while (64 * (tI + 1) - ((tI + 1) * tI) / 2 <= k) ++tI;
  while (64 * tI - (tI * (tI - 1)) / 2 > k) --tI;
  const int tJ = tI + (k - (64 * tI - (tI * (tI - 1)) / 2));

  __shared__ uint4 sAq[512];   // 8 KB
  __shared__ uint4 sBq[512];   // 8 KB
  __shared__ float redbuf[16];

  const int t = threadIdx.x;
  const int lane = t & 63, wave = t >> 6;
  const int wr = (wave >> 1) * 64, wc = (wave & 1) * 64;
  const int rowA0 = tI * 128, rowB0 = tJ * 128;

  // staging addresses (chunk-linear; LDS dest = wave-uniform base + lane*16)
  const unsigned short* gA[2];
  const unsigned short* gB[2];
  uint4* lA[2];
  uint4* lB[2];
#pragma unroll
  for (int c0 = 0; c0 < 2; ++c0) {
    const int c = t + c0 * 256;
    const int r = ((c >> 6) << 4) + (c & 15);
    const int kc = (c >> 4) & 3;
    gA[c0] = f + (size_t)(rowA0 + r) * DIM + kc * 8;
    gB[c0] = f + (size_t)(rowB0 + r) * DIM + kc * 8;
    lA[c0] = sAq + c;
    lB[c0] = sBq + c;
  }

  f32x4 acc[4][4];
#pragma unroll
  for (int a = 0; a < 4; ++a)
#pragma unroll
    for (int b = 0; b < 4; ++b) acc[a][b] = (f32x4){0.f, 0.f, 0.f, 0.f};

#pragma unroll
  for (int kk = 0; kk < 4; ++kk) {
    if (kk) __syncthreads();
#pragma unroll
    for (int c0 = 0; c0 < 2; ++c0) {
      __builtin_amdgcn_global_load_lds(
          (const __attribute__((address_space(1))) unsigned int*)(gA[c0] + kk * 32),
          (__attribute__((address_space(3))) unsigned int*)lA[c0], 16, 0, 0);
      __builtin_amdgcn_global_load_lds(
          (const __attribute__((address_space(1))) unsigned int*)(gB[c0] + kk * 32),
          (__attribute__((address_space(3))) unsigned int*)lB[c0], 16, 0, 0);
    }
    __syncthreads();  // barrier drains vmcnt -> LDS data visible
    bf16x8 fa[4], fbv[4];
#pragma unroll
    for (int x = 0; x < 4; ++x) {
      fa[x] = ((const bf16x8*)sAq)[(((wr >> 4) + x) << 6) + lane];
      fbv[x] = ((const bf16x8*)sBq)[(((wc >> 4) + x) << 6) + lane];
    }
#pragma unroll
    for (int tm = 0; tm < 4; ++tm)
#pragma unroll
      for (int tn = 0; tn < 4; ++tn)
        acc[tm][tn] =
            __builtin_amdgcn_mfma_f32_16x16x32_bf16(fa[tm], fbv[tn], acc[tm][tn], 0, 0, 0);
  }

  // C/D mapping (16x16x32): col = lane&15, row = (lane>>4)*4 + reg
  const int ibase = rowA0 + wr + (lane >> 4) * 4;
  const int jbase = rowB0 + wc + (lane & 15);
  const int dj = jbase - ibase;
  int li[4][4], lj[4];
#pragma unroll
  for (int tn = 0; tn < 4; ++tn) lj[tn] = labels[jbase + tn * 16];
#pragma unroll
  for (int tm = 0; tm < 4; ++tm)
#pragma unroll
    for (int r = 0; r < 4; ++r) li[tm][r] = labels[ibase + tm * 16 + r];

  if (tI == tJ) {  // block-uniform branch
    do_passes<true>(acc, li, lj, dj, lane, wave, redbuf, partials, k, t);
  } else {
    do_passes<false>(acc, li, lj, dj, lane, wave, redbuf, partials, k, t);
  }
}

// Merge NBLOCKS (m,s) partials for both streams; softplus(lse_p + lse_n).
__global__ __launch_bounds__(256) void finalize_kernel(const float4* __restrict__ partials,
                                                       float* __restrict__ out) {
  const int t = threadIdx.x;
  float mp = -1e30f, sp = 0.f, mn = -1e30f, sn = 0.f;
  for (int i = t; i < NBLOCKS; i += 256) {
    const float4 p = partials[i];
    {
      const float m = fmaxf(mp, p.x);
      sp = sp * __expf(mp - m) + p.y * __expf(p.x - m);
      mp = m;
    }
    {
      const float m = fmaxf(mn, p.z);
      sn = sn * __expf(mn - m) + p.w * __expf(p.z - m);
      mn = m;
    }
  }
  __shared__ float smp[256], ssp[256], smn[256], ssn[256];
  smp[t] = mp; ssp[t] = sp; smn[t] = mn; ssn[t] = sn;
  __syncthreads();
  for (int off = 128; off > 0; off >>= 1) {
    if (t < off) {
      {
        const float m2 = smp[t + off], s2 = ssp[t + off];
        const float m = fmaxf(smp[t], m2);
        ssp[t] = ssp[t] * __expf(smp[t] - m) + s2 * __expf(m2 - m);
        smp[t] = m;
      }
      {
        const float m2 = smn[t + off], s2 = ssn[t + off];
        const float m = fmaxf(smn[t], m2);
        ssn[t] = ssn[t] * __expf(smn[t] - m) + s2 * __expf(m2 - m);
        smn[t] = m;
      }
    }
    __syncthreads();
  }
  if (t == 0) {
    const float lsep = smp[0] + __logf(ssp[0]);
    const float lsen = smn[0] + __logf(ssn[0]);
    const float x = lsep + lsen;
    out[0] = fmaxf(x, 0.f) + log1pf(__expf(-fabsf(x)));  // stable softplus
  }
}

extern "C" void kernel_launch(void* const* d_in, const int* in_sizes, int n_in,
                              void* d_out, int out_size, void* d_ws, size_t ws_size,
                              hipStream_t stream) {
  const float* feat = (const float*)d_in[0];
  const int* labels = (const int*)d_in[1];
  float* out = (float*)d_out;

  unsigned short* fb = (unsigned short*)d_ws;                           // 2 MB
  float4* partials = (float4*)((char*)d_ws + (size_t)N_PTS * DIM * 2);  // 33 KB

  normalize_kernel<<<N_PTS / 4, 256, 0, stream>>>(feat, fb);
  pair_kernel<<<NBLOCKS, 256, 0, stream>>>(fb, labels, partials);
  finalize_kernel<<<1, 256, 0, stream>>>(partials, out);
}

// Round 3
// 129.010 us; speedup vs baseline: 1.1465x; 1.1465x over previous
//
#include <hip/hip_runtime.h>
#include <hip/hip_bf16.h>
#include <cstdint>

#define N_PTS 8192
#define DIM 128
#define NTILE 64       // 8192 / 128
#define NBLOCKS 2080   // NTILE*(NTILE+1)/2 upper-triangle tile blocks

typedef __attribute__((ext_vector_type(8))) __bf16 bf16x8;
typedef __attribute__((ext_vector_type(4))) float f32x4;

// RNE float -> bf16 bits (inputs finite)
__device__ __forceinline__ unsigned short f2bf(float x) {
  unsigned int u = __float_as_uint(x);
  return (unsigned short)((u + 0x7FFFu + ((u >> 16) & 1u)) >> 16);
}

// lp(s) = (1.25-s)(0.75-s)*256 (ap clamp never active for s<=1: 1.25-s>0)
__device__ __forceinline__ float lp_of(float s) {
  return __builtin_fmaf(s, __builtin_fmaf(s, 256.0f, -512.0f), 240.0f);
}
// ln(s) = max(s+0.25,0)*(s-0.25)*256 = 256*max(s,-0.25)^2 - 16 (exact incl. clamp)
__device__ __forceinline__ float ln_of(float s) {
  const float u = fmaxf(s, -0.25f);
  return __builtin_fmaf(u, u * 256.0f, -16.0f);
}
// merge (m2,s2) into (m,s): s <- s*e^(m-m') + s2*e^(m2-m')
__device__ __forceinline__ void lse_merge(float& m, float& s, float m2, float s2) {
  const float mm = fmaxf(m, m2);
  s = __builtin_fmaf(s, __expf(m - mm), s2 * __expf(m2 - mm));
  m = mm;
}

// One wave per row: L2-normalize (eps=1e-12), store bf16 bits. Also zero the
// completion counter used by pair_kernel's last-block finalize.
__global__ __launch_bounds__(256) void normalize_kernel(const float* __restrict__ feat,
                                                        unsigned short* __restrict__ fb,
                                                        int* __restrict__ counter) {
  if (blockIdx.x == 0 && threadIdx.x == 0) *counter = 0;
  const int row = blockIdx.x * 4 + (threadIdx.x >> 6);
  const int lane = threadIdx.x & 63;
  const float2 v = *(const float2*)(feat + row * DIM + lane * 2);
  float ss = v.x * v.x + v.y * v.y;
#pragma unroll
  for (int o = 32; o > 0; o >>= 1) ss += __shfl_xor(ss, o);
  const float inv = 1.0f / fmaxf(sqrtf(ss), 1e-12f);
  const unsigned int pack =
      (unsigned int)f2bf(v.x * inv) | ((unsigned int)f2bf(v.y * inv) << 16);
  *(unsigned int*)(fb + row * DIM + lane * 2) = pack;
}

// Online-logsumexp streaming epilogue: each acc element is consumed exactly once
// (no acc live-range across barriers -> no spills). 4 chains per stream (per r).
template <bool DIAG>
__device__ __forceinline__ void online_pass(const f32x4 (&acc)[4][2],
                                            const int* __restrict__ labels, int ibase,
                                            int dj, const int (&lj)[2], float (&mP)[4],
                                            float (&sP)[4], float (&mN)[4],
                                            float (&sN)[4]) {
#pragma unroll
  for (int tm = 0; tm < 4; ++tm) {
    int li[4];
#pragma unroll
    for (int r = 0; r < 4; ++r) li[r] = labels[ibase + tm * 16 + r];
#pragma unroll
    for (int tn = 0; tn < 2; ++tn) {
#pragma unroll
      for (int r = 0; r < 4; ++r) {
        const float s = acc[tm][tn][r];
        const bool eq = (li[r] == lj[tn]);
        bool pm = eq, nm = !eq;
        if (DIAG) {
          const bool valid = (dj + tn * 16 - tm * 16 - r) > 0;
          pm = pm && valid;
          nm = nm && valid;
        }
        const float l = eq ? lp_of(s) : ln_of(s);
        const float msel = pm ? mP[r] : mN[r];
        const float ssel = pm ? sP[r] : sN[r];
        const float mnew = fmaxf(msel, l);
        // msel=-1e30 & first element: e1=exp(-inf)=0, e2=exp(0)=1 -> snew=1. OK.
        const float snew =
            __builtin_fmaf(ssel, __expf(msel - mnew), __expf(l - mnew));
        mP[r] = pm ? mnew : mP[r];
        sP[r] = pm ? snew : sP[r];
        mN[r] = nm ? mnew : mN[r];
        sN[r] = nm ? snew : sN[r];
      }
    }
  }
}

// 128x128 tile per block, 512 threads (8 waves of 64x32). Chunk-linear LDS,
// global_load_lds width-16 staging, online-lse epilogue, last-block finalize.
__global__ __launch_bounds__(512, 4) void pair_kernel(const unsigned short* __restrict__ f,
                                                      const int* __restrict__ labels,
                                                      float4* __restrict__ partials,
                                                      int* __restrict__ counter,
                                                      float* __restrict__ out) {
  // decode linear block id -> (tI, tJ), tJ >= tI
  const int k = blockIdx.x;
  int tI = (int)((129.0 - sqrt(16641.0 - 8.0 * (double)k)) * 0.5);
  tI = tI < 0 ? 0 : (tI > 63 ? 63 : tI);
  while (64 * (tI + 1) - ((tI + 1) * tI) / 2 <= k) ++tI;
  while (64 * tI - (tI * (tI - 1)) / 2 > k) --tI;
  const int tJ = tI + (k - (64 * tI - (tI * (tI - 1)) / 2));

  __shared__ uint4 sAq[512];  // 8 KB
  __shared__ uint4 sBq[512];  // 8 KB
  __shared__ float4 fred[8];
  __shared__ int lastflag;

  const int t = threadIdx.x;
  const int lane = t & 63, wave = t >> 6;
  const int wri = wave >> 2, wci = wave & 3;  // wave tile: rows wri*64, cols wci*32
  const int rowA0 = tI * 128, rowB0 = tJ * 128;

  // staging: thread t owns 16B chunk t of each slab (chunk-linear layout)
  const int rstage = ((t >> 6) << 4) + (t & 15);
  const int kcs = ((t >> 4) & 3) * 8;
  const unsigned short* gA = f + (size_t)(rowA0 + rstage) * DIM + kcs;
  const unsigned short* gB = f + (size_t)(rowB0 + rstage) * DIM + kcs;

  f32x4 acc[4][2];
#pragma unroll
  for (int a = 0; a < 4; ++a)
#pragma unroll
    for (int b = 0; b < 2; ++b) acc[a][b] = (f32x4){0.f, 0.f, 0.f, 0.f};

#pragma unroll
  for (int kk = 0; kk < 4; ++kk) {
    if (kk) __syncthreads();
    __builtin_amdgcn_global_load_lds(
        (const __attribute__((address_space(1))) unsigned int*)(gA + kk * 32),
        (__attribute__((address_space(3))) unsigned int*)(sAq + t), 16, 0, 0);
    __builtin_amdgcn_global_load_lds(
        (const __attribute__((address_space(1))) unsigned int*)(gB + kk * 32),
        (__attribute__((address_space(3))) unsigned int*)(sBq + t), 16, 0, 0);
    __syncthreads();  // drains vmcnt -> LDS visible
    bf16x8 fa[4], fbv[2];
#pragma unroll
    for (int x = 0; x < 4; ++x)
      fa[x] = ((const bf16x8*)sAq)[((wri * 4 + x) << 6) + lane];
#pragma unroll
    for (int y = 0; y < 2; ++y)
      fbv[y] = ((const bf16x8*)sBq)[((wci * 2 + y) << 6) + lane];
#pragma unroll
    for (int tm = 0; tm < 4; ++tm)
#pragma unroll
      for (int tn = 0; tn < 2; ++tn)
        acc[tm][tn] =
            __builtin_amdgcn_mfma_f32_16x16x32_bf16(fa[tm], fbv[tn], acc[tm][tn], 0, 0, 0);
  }

  // C/D mapping (16x16x32): col = lane&15, row = (lane>>4)*4 + reg
  const int ibase = rowA0 + wri * 64 + (lane >> 4) * 4;
  const int jbase = rowB0 + wci * 32 + (lane & 15);
  const int dj = jbase - ibase;  // on diag tiles rowA0==rowB0
  int lj[2];
#pragma unroll
  for (int tn = 0; tn < 2; ++tn) lj[tn] = labels[jbase + tn * 16];

  float mP[4], sP[4], mN[4], sN[4];
#pragma unroll
  for (int r = 0; r < 4; ++r) { mP[r] = -1e30f; sP[r] = 0.f; mN[r] = -1e30f; sN[r] = 0.f; }

  if (tI == tJ) {
    online_pass<true>(acc, labels, ibase, dj, lj, mP, sP, mN, sN);
  } else {
    online_pass<false>(acc, labels, ibase, dj, lj, mP, sP, mN, sN);
  }

  // merge 4 chains -> 1 per stream
  float mp = mP[0], sp = sP[0], mn = mN[0], sn = sN[0];
#pragma unroll
  for (int r = 1; r < 4; ++r) {
    lse_merge(mp, sp, mP[r], sP[r]);
    lse_merge(mn, sn, mN[r], sN[r]);
  }
  // wave butterfly
#pragma unroll
  for (int o = 32; o > 0; o >>= 1) {
    const float am = __shfl_xor(mp, o), as = __shfl_xor(sp, o);
    lse_merge(mp, sp, am, as);
    const float bm = __shfl_xor(mn, o), bs = __shfl_xor(sn, o);
    lse_merge(mn, sn, bm, bs);
  }
  if (lane == 0) fred[wave] = make_float4(mp, sp, mn, sn);
  __syncthreads();
  if (t == 0) {
    float Mp = -1e30f, Sp = 0.f, Mn = -1e30f, Sn = 0.f;
#pragma unroll
    for (int w = 0; w < 8; ++w) {
      const float4 q = fred[w];
      lse_merge(Mp, Sp, q.x, q.y);
      lse_merge(Mn, Sn, q.z, q.w);
    }
    partials[k] = make_float4(Mp, Sp, Mn, Sn);
    __threadfence();  // make partial visible before counting
    lastflag = (atomicAdd(counter, 1) == NBLOCKS - 1);
  }
  __syncthreads();
  if (!lastflag) return;

  // ---- last block: merge all partials, softplus, write out ----
  __threadfence();  // acquire: see other blocks' partials
  float Mp = -1e30f, Sp = 0.f, Mn = -1e30f, Sn = 0.f;
  for (int i = t; i < NBLOCKS; i += 512) {
    const float4 p = partials[i];
    lse_merge(Mp, Sp, p.x, p.y);
    lse_merge(Mn, Sn, p.z, p.w);
  }
#pragma unroll
  for (int o = 32; o > 0; o >>= 1) {
    const float am = __shfl_xor(Mp, o), as = __shfl_xor(Sp, o);
    lse_merge(Mp, Sp, am, as);
    const float bm = __shfl_xor(Mn, o), bs = __shfl_xor(Sn, o);
    lse_merge(Mn, Sn, bm, bs);
  }
  if (lane == 0) fred[wave] = make_float4(Mp, Sp, Mn, Sn);
  __syncthreads();
  if (t == 0) {
    float mpf = -1e30f, spf = 0.f, mnf = -1e30f, snf = 0.f;
#pragma unroll
    for (int w = 0; w < 8; ++w) {
      const float4 q = fred[w];
      lse_merge(mpf, spf, q.x, q.y);
      lse_merge(mnf, snf, q.z, q.w);
    }
    const float x = (mpf + __logf(spf)) + (mnf + __logf(snf));
    out[0] = fmaxf(x, 0.f) + log1pf(__expf(-fabsf(x)));  // stable softplus
  }
}

extern "C" void kernel_launch(void* const* d_in, const int* in_sizes, int n_in,
                              void* d_out, int out_size, void* d_ws, size_t ws_size,
                              hipStream_t stream) {
  const float* feat = (const float*)d_in[0];
  const int* labels = (const int*)d_in[1];
  float* out = (float*)d_out;

  unsigned short* fb = (unsigned short*)d_ws;  // 2 MB
  float4* partials = (float4*)((char*)d_ws + (size_t)N_PTS * DIM * 2);
  int* counter = (int*)((char*)d_ws + (size_t)N_PTS * DIM * 2 + NBLOCKS * sizeof(float4));

  normalize_kernel<<<N_PTS / 4, 256, 0, stream>>>(feat, fb, counter);
  pair_kernel<<<NBLOCKS, 512, 0, stream>>>(fb, labels, partials, counter, out);
}